// Round 1
// baseline (373.178 us; speedup 1.0000x reference)
//
#include <hip/hip_runtime.h>
#include <stdint.h>

// Problem constants: B=2, N=2048, K=48, H=128, 3H=384, FF=512
#define XP 392      // x_tile pitch (bf16 elems): 784 B = 196 dwords (196%32=4, conflict-safe)
#define MP 136      // mid pitch: 272 B = 68 dwords (68%32=4)
#define EPIP 132    // epilogue f32 pitch: 132 dwords (132%32=4)
#define FFP 520     // ffn mid pitch: 1040 B = 260 dwords (260%32=4)

typedef __attribute__((ext_vector_type(8))) short bf16x8;
typedef __attribute__((ext_vector_type(4))) float f32x4;

__device__ __forceinline__ f32x4 mfma16(bf16x8 a, bf16x8 b, f32x4 c) {
  return __builtin_amdgcn_mfma_f32_16x16x32_bf16(a, b, c, 0, 0, 0);
}

__device__ __forceinline__ uint16_t f2b(float f) {
  union { float f; uint32_t u; } v; v.f = f;
  uint32_t u = v.u;
  uint32_t r = u + 0x7fffu + ((u >> 16) & 1u);
  return (uint16_t)(r >> 16);
}
__device__ __forceinline__ float b2f(uint16_t h) {
  union { uint32_t u; float f; } v; v.u = ((uint32_t)h) << 16;
  return v.f;
}
__device__ __forceinline__ uint32_t pk2(float a, float b) {
  return (uint32_t)f2b(a) | ((uint32_t)f2b(b) << 16);
}
__device__ __forceinline__ float gelu_f(float x) {
  // tanh-form GELU (max abs err ~3e-3 vs erf form; threshold is bf16-scale)
  float z = 0.7978845608028654f * (x + 0.044715f * x * x * x);
  float e = __expf(2.0f * z);
  float t = 1.0f - 2.0f / (e + 1.0f);
  return 0.5f * x * (1.0f + t);
}

// ---------------- prep: bf16 h_V + transposed bf16 weights ----------------
__global__ __launch_bounds__(256) void k_prep(
    const float* __restrict__ hV,
    const float* __restrict__ W1, const float* __restrict__ W2, const float* __restrict__ W3,
    const float* __restrict__ WdIn, const float* __restrict__ WdOut,
    const float* __restrict__ W11, const float* __restrict__ W12, const float* __restrict__ W13,
    uint16_t* __restrict__ hVb,
    uint16_t* __restrict__ W1t, uint16_t* __restrict__ W2t, uint16_t* __restrict__ W3t,
    uint16_t* __restrict__ WdInT, uint16_t* __restrict__ WdOutT,
    uint16_t* __restrict__ W11t, uint16_t* __restrict__ W12t, uint16_t* __restrict__ W13t) {
  int i = blockIdx.x * 256 + threadIdx.x;
  if (i < 524288) { hVb[i] = f2b(hV[i]); return; }
  int j = i - 524288;
  if (j < 49152) { int n = j / 384, k = j - n * 384; W1t[j] = f2b(W1[k * 128 + n]); return; }
  j -= 49152;
  if (j < 16384) { int n = j >> 7, k = j & 127; W2t[j] = f2b(W2[k * 128 + n]); return; }
  j -= 16384;
  if (j < 16384) { int n = j >> 7, k = j & 127; W3t[j] = f2b(W3[k * 128 + n]); return; }
  j -= 16384;
  if (j < 65536) { int n = j >> 7, k = j & 127; WdInT[j] = f2b(WdIn[k * 512 + n]); return; }
  j -= 65536;
  if (j < 65536) { int n = j >> 9, k = j & 511; WdOutT[j] = f2b(WdOut[k * 128 + n]); return; }
  j -= 65536;
  if (j < 49152) { int n = j / 384, k = j - n * 384; W11t[j] = f2b(W11[k * 128 + n]); return; }
  j -= 49152;
  if (j < 16384) { int n = j >> 7, k = j & 127; W12t[j] = f2b(W12[k * 128 + n]); return; }
  j -= 16384;
  if (j < 16384) { int n = j >> 7, k = j & 127; W13t[j] = f2b(W13[k * 128 + n]); return; }
}

// x_tile build: rows k=0..47, cols [hV(own) | hE | hV(nbr)]
#define BUILD_XT(GSRC)                                                              \
  do {                                                                              \
    for (int idx = tid; idx < 48 * 48; idx += 256) {                                \
      int k_ = idx / 48;                                                            \
      int c_ = idx - k_ * 48;                                                       \
      uint4 v_;                                                                     \
      if (c_ < 16) {                                                                \
        v_ = *(const uint4*)((GSRC) + bn * 128 + (c_ << 3));                        \
      } else if (c_ < 32) {                                                         \
        const float* s_ = hE + (size_t)(bn * 48 + k_) * 128 + ((c_ - 16) << 3);     \
        float4 f0_ = *(const float4*)s_;                                            \
        float4 f1_ = *(const float4*)(s_ + 4);                                      \
        v_ = make_uint4(pk2(f0_.x, f0_.y), pk2(f0_.z, f0_.w),                       \
                        pk2(f1_.x, f1_.y), pk2(f1_.z, f1_.w));                      \
      } else {                                                                      \
        v_ = *(const uint4*)((GSRC) + nbr[k_] * 128 + ((c_ - 32) << 3));            \
      }                                                                             \
      *(uint4*)(xt + k_ * XP + (c_ << 3)) = v_;                                     \
    }                                                                               \
  } while (0)

// MFMA layer, K=384, A = xt
#define LAYER384(WT, ACC)                                                           \
  do {                                                                              \
    const uint16_t* wr0_ = (WT) + (w * 32 + l15) * 384 + lg * 8;                    \
    const uint16_t* wr1_ = (WT) + (w * 32 + 16 + l15) * 384 + lg * 8;               \
    for (int ks = 0; ks < 12; ++ks) {                                               \
      bf16x8 bA_ = *(const bf16x8*)(wr0_ + ks * 32);                                \
      bf16x8 bB_ = *(const bf16x8*)(wr1_ + ks * 32);                                \
      _Pragma("unroll") for (int m = 0; m < 3; ++m) {                               \
        bf16x8 a_ = *(const bf16x8*)(xt + (m * 16 + l15) * XP + ks * 32 + lg * 8);  \
        ACC[m][0] = mfma16(a_, bA_, ACC[m][0]);                                     \
        ACC[m][1] = mfma16(a_, bB_, ACC[m][1]);                                     \
      }                                                                             \
    }                                                                               \
  } while (0)

// MFMA layer, K=128, A = ASRC (pitch MP)
#define LAYER128(WT, ASRC, ACC)                                                     \
  do {                                                                              \
    const uint16_t* wr0_ = (WT) + (w * 32 + l15) * 128 + lg * 8;                    \
    const uint16_t* wr1_ = (WT) + (w * 32 + 16 + l15) * 128 + lg * 8;               \
    for (int ks = 0; ks < 4; ++ks) {                                                \
      bf16x8 bA_ = *(const bf16x8*)(wr0_ + ks * 32);                                \
      bf16x8 bB_ = *(const bf16x8*)(wr1_ + ks * 32);                                \
      _Pragma("unroll") for (int m = 0; m < 3; ++m) {                               \
        bf16x8 a_ = *(const bf16x8*)((ASRC) + (m * 16 + l15) * MP + ks * 32 + lg * 8); \
        ACC[m][0] = mfma16(a_, bA_, ACC[m][0]);                                     \
        ACC[m][1] = mfma16(a_, bB_, ACC[m][1]);                                     \
      }                                                                             \
    }                                                                               \
  } while (0)

// bias + gelu + bf16 store to DST (pitch MP)
#define GSTORE(ACC, BIAS, DST)                                                      \
  do {                                                                              \
    float bA_ = (BIAS)[w * 32 + l15];                                               \
    float bB_ = (BIAS)[w * 32 + 16 + l15];                                          \
    _Pragma("unroll") for (int m = 0; m < 3; ++m)                                   \
    _Pragma("unroll") for (int r = 0; r < 4; ++r) {                                 \
      int row_ = m * 16 + lg * 4 + r;                                               \
      (DST)[row_ * MP + w * 32 + l15] = f2b(gelu_f(ACC[m][0][r] + bA_));            \
      (DST)[row_ * MP + w * 32 + 16 + l15] = f2b(gelu_f(ACC[m][1][r] + bB_));       \
    }                                                                               \
  } while (0)

// ---------------- K1: node message MLP + masked sum + LN1 ----------------
__global__ __launch_bounds__(256, 2) void k_node(
    const float* __restrict__ hV, const float* __restrict__ hE,
    const int* __restrict__ eidx, const float* __restrict__ maskA,
    const float* __restrict__ bias1, const float* __restrict__ bias2,
    const float* __restrict__ bias3,
    const float* __restrict__ g1, const float* __restrict__ be1,
    const uint16_t* __restrict__ hVb,
    const uint16_t* __restrict__ W1t, const uint16_t* __restrict__ W2t,
    const uint16_t* __restrict__ W3t,
    float* __restrict__ hV1, uint16_t* __restrict__ hV1b) {
  __shared__ __align__(16) unsigned char lds[64640];
  uint16_t* xt = (uint16_t*)lds;                 // [48][392] bf16
  uint16_t* midA = (uint16_t*)(lds + 37632);     // [48][136]
  uint16_t* midB = (uint16_t*)(lds + 50688);     // [48][136]
  float* dh = (float*)(lds + 63744);             // [128]
  int* nbr = (int*)(lds + 64256);                // [48]
  float* amask = (float*)(lds + 64448);          // [48]

  const int tid = threadIdx.x;
  const int lane = tid & 63;
  const int w = tid >> 6;
  const int l15 = lane & 15;
  const int lg = lane >> 4;
  const int bn = blockIdx.x;      // b*2048 + n
  const int b = bn >> 11;

  if (tid < 48) {
    nbr[tid] = (b << 11) + eidx[bn * 48 + tid];
    amask[tid] = maskA[bn * 48 + tid];
  }
  __syncthreads();

  BUILD_XT(hVb);
  __syncthreads();

  f32x4 acc1[3][2] = {};
  LAYER384(W1t, acc1);
  GSTORE(acc1, bias1, midA);
  __syncthreads();

  f32x4 acc2[3][2] = {};
  LAYER128(W2t, midA, acc2);
  GSTORE(acc2, bias2, midB);
  __syncthreads();

  f32x4 acc3[3][2] = {};
  LAYER128(W3t, midB, acc3);

  // masked column sums over the 48 edge rows
  {
    float bA = bias3[w * 32 + l15];
    float bB = bias3[w * 32 + 16 + l15];
    float s0 = 0.f, s1 = 0.f;
#pragma unroll
    for (int m = 0; m < 3; ++m)
#pragma unroll
      for (int r = 0; r < 4; ++r) {
        int row = m * 16 + lg * 4 + r;
        float mk = amask[row];
        s0 += (acc3[m][0][r] + bA) * mk;
        s1 += (acc3[m][1][r] + bB) * mk;
      }
    s0 += __shfl_xor(s0, 16); s0 += __shfl_xor(s0, 32);
    s1 += __shfl_xor(s1, 16); s1 += __shfl_xor(s1, 32);
    if (lg == 0) { dh[w * 32 + l15] = s0; dh[w * 32 + 16 + l15] = s1; }
  }
  __syncthreads();

  if (w == 0) {
    const float inv = 1.0f / 30.0f;
    float x0 = hV[bn * 128 + lane] + dh[lane] * inv;
    float x1 = hV[bn * 128 + 64 + lane] + dh[64 + lane] * inv;
    float s = x0 + x1, q = x0 * x0 + x1 * x1;
#pragma unroll
    for (int off = 1; off < 64; off <<= 1) {
      s += __shfl_xor(s, off);
      q += __shfl_xor(q, off);
    }
    float mean = s * (1.0f / 128.0f);
    float var = q * (1.0f / 128.0f) - mean * mean;
    float rstd = rsqrtf(var + 1e-5f);
    float y0 = (x0 - mean) * rstd * g1[lane] + be1[lane];
    float y1 = (x1 - mean) * rstd * g1[64 + lane] + be1[64 + lane];
    hV1[bn * 128 + lane] = y0;
    hV1[bn * 128 + 64 + lane] = y1;
    hV1b[bn * 128 + lane] = f2b(y0);
    hV1b[bn * 128 + 64 + lane] = f2b(y1);
  }
}

// ---------------- K2: position-wise FFN + LN2 + mask_V ----------------
__global__ __launch_bounds__(256, 2) void k_ffn(
    const float* __restrict__ hV1, const uint16_t* __restrict__ hV1b,
    const float* __restrict__ maskV,
    const float* __restrict__ bdin, const float* __restrict__ bdout,
    const float* __restrict__ g2, const float* __restrict__ be2,
    const uint16_t* __restrict__ WdInT, const uint16_t* __restrict__ WdOutT,
    float* __restrict__ outV, uint16_t* __restrict__ hV2b) {
  __shared__ __align__(16) unsigned char lds[20992];
  uint16_t* xa = (uint16_t*)lds;             // [16][136]
  uint16_t* mf = (uint16_t*)(lds + 4352);    // [16][520]
  float* epi = (float*)(lds + 4352);         // [16][132] overlays mf (post-barrier)

  const int tid = threadIdx.x;
  const int lane = tid & 63;
  const int w = tid >> 6;
  const int l15 = lane & 15;
  const int lg = lane >> 4;
  const int node0 = blockIdx.x * 16;

  {
    int row = tid >> 4, c = tid & 15;
    *(uint4*)(xa + row * 136 + (c << 3)) =
        *(const uint4*)(hV1b + (node0 + row) * 128 + (c << 3));
  }
  __syncthreads();

  // layer A: [16x128] @ [128x512]
  f32x4 acc[8] = {};
  {
    const uint16_t* ar = xa + l15 * 136 + lg * 8;
    for (int ks = 0; ks < 4; ++ks) {
      bf16x8 a = *(const bf16x8*)(ar + ks * 32);
#pragma unroll
      for (int j = 0; j < 8; ++j) {
        bf16x8 bb = *(const bf16x8*)(WdInT + ((w * 8 + j) * 16 + l15) * 128 + ks * 32 + lg * 8);
        acc[j] = mfma16(a, bb, acc[j]);
      }
    }
  }
#pragma unroll
  for (int j = 0; j < 8; ++j) {
    int col = (w * 8 + j) * 16 + l15;
    float bs = bdin[col];
#pragma unroll
    for (int r = 0; r < 4; ++r) {
      int row = lg * 4 + r;
      mf[row * FFP + col] = f2b(gelu_f(acc[j][r] + bs));
    }
  }
  __syncthreads();

  // layer B: [16x512] @ [512x128]
  f32x4 acc2[2] = {};
  {
    const uint16_t* mr = mf + l15 * FFP + lg * 8;
    for (int ks = 0; ks < 16; ++ks) {
      bf16x8 a = *(const bf16x8*)(mr + ks * 32);
#pragma unroll
      for (int t = 0; t < 2; ++t) {
        bf16x8 bb = *(const bf16x8*)(WdOutT + ((w * 2 + t) * 16 + l15) * 512 + ks * 32 + lg * 8);
        acc2[t] = mfma16(a, bb, acc2[t]);
      }
    }
  }
  __syncthreads();  // all mf reads done before epi overlays it
#pragma unroll
  for (int t = 0; t < 2; ++t) {
    int col = (w * 2 + t) * 16 + l15;
    float bs = bdout[col];
#pragma unroll
    for (int r = 0; r < 4; ++r) {
      int row = lg * 4 + r;
      epi[row * EPIP + col] = acc2[t][r] + bs;
    }
  }
  __syncthreads();

  // per-node LN2 + mask_V; wave w handles rows 4w..4w+3
#pragma unroll
  for (int rr = 0; rr < 4; ++rr) {
    int row = w * 4 + rr;
    int node = node0 + row;
    float x0 = epi[row * EPIP + lane] + hV1[node * 128 + lane];
    float x1 = epi[row * EPIP + 64 + lane] + hV1[node * 128 + 64 + lane];
    float s = x0 + x1, q = x0 * x0 + x1 * x1;
#pragma unroll
    for (int off = 1; off < 64; off <<= 1) {
      s += __shfl_xor(s, off);
      q += __shfl_xor(q, off);
    }
    float mean = s * (1.0f / 128.0f);
    float var = q * (1.0f / 128.0f) - mean * mean;
    float rstd = rsqrtf(var + 1e-5f);
    float mv = maskV[node];
    float y0 = mv * ((x0 - mean) * rstd * g2[lane] + be2[lane]);
    float y1 = mv * ((x1 - mean) * rstd * g2[64 + lane] + be2[64 + lane]);
    outV[node * 128 + lane] = y0;
    outV[node * 128 + 64 + lane] = y1;
    hV2b[node * 128 + lane] = f2b(y0);
    hV2b[node * 128 + 64 + lane] = f2b(y1);
  }
}

// ---------------- K3: edge MLP + residual + LN3 ----------------
__global__ __launch_bounds__(256, 2) void k_edge(
    const float* __restrict__ hE, const int* __restrict__ eidx,
    const float* __restrict__ bias1, const float* __restrict__ bias2,
    const float* __restrict__ bias3,
    const float* __restrict__ g3, const float* __restrict__ be3,
    const uint16_t* __restrict__ hV2b,
    const uint16_t* __restrict__ W1t, const uint16_t* __restrict__ W2t,
    const uint16_t* __restrict__ W3t,
    float* __restrict__ outE) {
  __shared__ __align__(16) unsigned char lds[64640];
  uint16_t* xt = (uint16_t*)lds;                 // [48][392]
  uint16_t* midA = (uint16_t*)(lds + 37632);     // [48][136]
  uint16_t* midB = (uint16_t*)(lds + 50688);     // [48][136]
  float* epi = (float*)(lds + 37632);            // [48][132] overlays midA+midB
  int* nbr = (int*)(lds + 64256);                // [48]

  const int tid = threadIdx.x;
  const int lane = tid & 63;
  const int w = tid >> 6;
  const int l15 = lane & 15;
  const int lg = lane >> 4;
  const int bn = blockIdx.x;
  const int b = bn >> 11;

  if (tid < 48) nbr[tid] = (b << 11) + eidx[bn * 48 + tid];
  __syncthreads();

  BUILD_XT(hV2b);
  __syncthreads();

  f32x4 acc1[3][2] = {};
  LAYER384(W1t, acc1);
  GSTORE(acc1, bias1, midA);
  __syncthreads();

  f32x4 acc2[3][2] = {};
  LAYER128(W2t, midA, acc2);
  GSTORE(acc2, bias2, midB);
  __syncthreads();

  f32x4 acc3[3][2] = {};
  LAYER128(W3t, midB, acc3);
  __syncthreads();  // all midB reads done before epi overlays it

  {
    float bA = bias3[w * 32 + l15];
    float bB = bias3[w * 32 + 16 + l15];
#pragma unroll
    for (int m = 0; m < 3; ++m)
#pragma unroll
      for (int r = 0; r < 4; ++r) {
        int row = m * 16 + lg * 4 + r;
        epi[row * EPIP + w * 32 + l15] = acc3[m][0][r] + bA;
        epi[row * EPIP + w * 32 + 16 + l15] = acc3[m][1][r] + bB;
      }
  }
  __syncthreads();

  // per-edge-row LN3 with f32 residual; wave w handles rows 12w..12w+11
#pragma unroll
  for (int rr = 0; rr < 12; ++rr) {
    int row = w * 12 + rr;
    int e = bn * 48 + row;
    float x0 = epi[row * EPIP + lane] + hE[(size_t)e * 128 + lane];
    float x1 = epi[row * EPIP + 64 + lane] + hE[(size_t)e * 128 + 64 + lane];
    float s = x0 + x1, q = x0 * x0 + x1 * x1;
#pragma unroll
    for (int off = 1; off < 64; off <<= 1) {
      s += __shfl_xor(s, off);
      q += __shfl_xor(q, off);
    }
    float mean = s * (1.0f / 128.0f);
    float var = q * (1.0f / 128.0f) - mean * mean;
    float rstd = rsqrtf(var + 1e-5f);
    float y0 = (x0 - mean) * rstd * g3[lane] + be3[lane];
    float y1 = (x1 - mean) * rstd * g3[64 + lane] + be3[64 + lane];
    outE[(size_t)e * 128 + lane] = y0;
    outE[(size_t)e * 128 + 64 + lane] = y1;
  }
}

extern "C" void kernel_launch(void* const* d_in, const int* in_sizes, int n_in,
                              void* d_out, int out_size, void* d_ws, size_t ws_size,
                              hipStream_t stream) {
  const float* hV = (const float*)d_in[0];
  const float* hE = (const float*)d_in[1];
  const int* eidx = (const int*)d_in[2];
  const float* maskV = (const float*)d_in[3];
  const float* maskA = (const float*)d_in[4];
  const float* W1 = (const float*)d_in[5];   const float* b1 = (const float*)d_in[6];
  const float* W2 = (const float*)d_in[7];   const float* b2 = (const float*)d_in[8];
  const float* W3 = (const float*)d_in[9];   const float* b3 = (const float*)d_in[10];
  const float* WdIn = (const float*)d_in[11];  const float* bdin = (const float*)d_in[12];
  const float* WdOut = (const float*)d_in[13]; const float* bdout = (const float*)d_in[14];
  const float* W11 = (const float*)d_in[15]; const float* b11 = (const float*)d_in[16];
  const float* W12 = (const float*)d_in[17]; const float* b12 = (const float*)d_in[18];
  const float* W13 = (const float*)d_in[19]; const float* b13 = (const float*)d_in[20];
  const float* n1g = (const float*)d_in[21]; const float* n1b = (const float*)d_in[22];
  const float* n2g = (const float*)d_in[23]; const float* n2b = (const float*)d_in[24];
  const float* n3g = (const float*)d_in[25]; const float* n3b = (const float*)d_in[26];

  char* ws = (char*)d_ws;
  uint16_t* hVb    = (uint16_t*)(ws + 0);         // 1,048,576 B
  uint16_t* W1t    = (uint16_t*)(ws + 1048576);   // 98,304
  uint16_t* W2t    = (uint16_t*)(ws + 1146880);   // 32,768
  uint16_t* W3t    = (uint16_t*)(ws + 1179648);   // 32,768
  uint16_t* WdInT  = (uint16_t*)(ws + 1212416);   // 131,072
  uint16_t* WdOutT = (uint16_t*)(ws + 1343488);   // 131,072
  uint16_t* W11t   = (uint16_t*)(ws + 1474560);   // 98,304
  uint16_t* W12t   = (uint16_t*)(ws + 1572864);   // 32,768
  uint16_t* W13t   = (uint16_t*)(ws + 1605632);   // 32,768
  float*    hV1    = (float*)(ws + 1638400);      // 2,097,152 (f32)
  uint16_t* hV1b   = (uint16_t*)(ws + 3735552);   // 1,048,576
  uint16_t* hV2b   = (uint16_t*)(ws + 4784128);   // 1,048,576  (total 5.83 MB)

  float* outV = (float*)d_out;
  float* outE = (float*)d_out + 524288;

  k_prep<<<3200, 256, 0, stream>>>(hV, W1, W2, W3, WdIn, WdOut, W11, W12, W13,
                                   hVb, W1t, W2t, W3t, WdInT, WdOutT, W11t, W12t, W13t);
  k_node<<<4096, 256, 0, stream>>>(hV, hE, eidx, maskA, b1, b2, b3, n1g, n1b,
                                   hVb, W1t, W2t, W3t, hV1, hV1b);
  k_ffn<<<256, 256, 0, stream>>>(hV1, hV1b, maskV, bdin, bdout, n2g, n2b,
                                 WdInT, WdOutT, outV, hV2b);
  k_edge<<<4096, 256, 0, stream>>>(hE, eidx, b11, b12, b13, n3g, n3b,
                                   hV2b, W11t, W12t, W13t, outE);
}

// Round 2
// 233.308 us; speedup vs baseline: 1.5995x; 1.5995x over previous
//
#include <hip/hip_runtime.h>
#include <stdint.h>

// Problem constants: B=2, N=2048, K=48, H=128, 3H=384, FF=512
#define XP2 264     // x_tile pitch (bf16): 528 B = 132 dwords (132%32=4, 2-way only)
#define MP 136      // mid pitch: 272 B = 68 dwords (68%32=4)
#define EPIP 132    // epilogue f32 pitch: 132 dwords (132%32=4)
#define FFP 520     // ffn mid pitch: 1040 B = 260 dwords (260%32=4)

typedef __attribute__((ext_vector_type(8))) short bf16x8;
typedef __attribute__((ext_vector_type(4))) float f32x4;

__device__ __forceinline__ f32x4 mfma16(bf16x8 a, bf16x8 b, f32x4 c) {
  return __builtin_amdgcn_mfma_f32_16x16x32_bf16(a, b, c, 0, 0, 0);
}

__device__ __forceinline__ uint16_t f2b(float f) {
  union { float f; uint32_t u; } v; v.f = f;
  uint32_t u = v.u;
  uint32_t r = u + 0x7fffu + ((u >> 16) & 1u);
  return (uint16_t)(r >> 16);
}
__device__ __forceinline__ uint32_t pk2(float a, float b) {
  return (uint32_t)f2b(a) | ((uint32_t)f2b(b) << 16);
}
__device__ __forceinline__ float gelu_f(float x) {
  // tanh-form GELU (max abs err ~3e-3 vs erf form; threshold is bf16-scale)
  float z = 0.7978845608028654f * (x + 0.044715f * x * x * x);
  float e = __expf(2.0f * z);
  float t = 1.0f - 2.0f / (e + 1.0f);
  return 0.5f * x * (1.0f + t);
}

// ---------------- prep: bf16 h_V + transposed bf16 weights ----------------
__global__ __launch_bounds__(256) void k_prep(
    const float* __restrict__ hV,
    const float* __restrict__ W1, const float* __restrict__ W2, const float* __restrict__ W3,
    const float* __restrict__ WdIn, const float* __restrict__ WdOut,
    const float* __restrict__ W11, const float* __restrict__ W12, const float* __restrict__ W13,
    uint16_t* __restrict__ hVb,
    uint16_t* __restrict__ W1t, uint16_t* __restrict__ W2t, uint16_t* __restrict__ W3t,
    uint16_t* __restrict__ WdInT, uint16_t* __restrict__ WdOutT,
    uint16_t* __restrict__ W11t, uint16_t* __restrict__ W12t, uint16_t* __restrict__ W13t) {
  int i = blockIdx.x * 256 + threadIdx.x;
  if (i < 524288) { hVb[i] = f2b(hV[i]); return; }
  int j = i - 524288;
  if (j < 49152) { int n = j / 384, k = j - n * 384; W1t[j] = f2b(W1[k * 128 + n]); return; }
  j -= 49152;
  if (j < 16384) { int n = j >> 7, k = j & 127; W2t[j] = f2b(W2[k * 128 + n]); return; }
  j -= 16384;
  if (j < 16384) { int n = j >> 7, k = j & 127; W3t[j] = f2b(W3[k * 128 + n]); return; }
  j -= 16384;
  if (j < 65536) { int n = j >> 7, k = j & 127; WdInT[j] = f2b(WdIn[k * 512 + n]); return; }
  j -= 65536;
  if (j < 65536) { int n = j >> 9, k = j & 511; WdOutT[j] = f2b(WdOut[k * 128 + n]); return; }
  j -= 65536;
  if (j < 49152) { int n = j / 384, k = j - n * 384; W11t[j] = f2b(W11[k * 128 + n]); return; }
  j -= 49152;
  if (j < 16384) { int n = j >> 7, k = j & 127; W12t[j] = f2b(W12[k * 128 + n]); return; }
  j -= 16384;
  if (j < 16384) { int n = j >> 7, k = j & 127; W13t[j] = f2b(W13[k * 128 + n]); return; }
}

// ---------------- k_vec: C[i][n] = sum_{k<128} Xb[i][k] * Wt[n][k]  ----------------
// Xb: [4096][128] bf16; Wt: [128][384] bf16 (only k<128 used); C: [4096][128] f32
__global__ __launch_bounds__(256) void k_vec(
    const uint16_t* __restrict__ Xb, const uint16_t* __restrict__ Wt,
    float* __restrict__ C) {
  const int tid = threadIdx.x;
  const int lane = tid & 63, w = tid >> 6, l15 = lane & 15, lg = lane >> 4;
  const int row0 = blockIdx.x * 64 + w * 16;
  f32x4 acc[8] = {};
#pragma unroll
  for (int ks = 0; ks < 4; ++ks) {
    bf16x8 a = *(const bf16x8*)(Xb + (row0 + l15) * 128 + ks * 32 + lg * 8);
#pragma unroll
    for (int j = 0; j < 8; ++j) {
      bf16x8 bb = *(const bf16x8*)(Wt + (j * 16 + l15) * 384 + ks * 32 + lg * 8);
      acc[j] = mfma16(a, bb, acc[j]);
    }
  }
#pragma unroll
  for (int j = 0; j < 8; ++j)
#pragma unroll
    for (int r = 0; r < 4; ++r)
      C[(row0 + lg * 4 + r) * 128 + j * 16 + l15] = acc[j][r];
}

// x_tile build: rows k=0..47, cols [hE(128) | hV_nbr(128)] as bf16, pitch XP2
#define BUILD_XT(GSRC)                                                              \
  do {                                                                              \
    for (int idx = tid; idx < 48 * 32; idx += 256) {                                \
      int k_ = idx >> 5;                                                            \
      int c_ = idx & 31;                                                            \
      uint4 v_;                                                                     \
      if (c_ < 16) {                                                                \
        const float* s_ = hE + (size_t)(bn * 48 + k_) * 128 + (c_ << 3);            \
        float4 f0_ = *(const float4*)s_;                                            \
        float4 f1_ = *(const float4*)(s_ + 4);                                      \
        v_ = make_uint4(pk2(f0_.x, f0_.y), pk2(f0_.z, f0_.w),                       \
                        pk2(f1_.x, f1_.y), pk2(f1_.z, f1_.w));                      \
      } else {                                                                      \
        v_ = *(const uint4*)((GSRC) + nbr[k_] * 128 + ((c_ - 16) << 3));            \
      }                                                                             \
      *(uint4*)(xt + k_ * XP2 + (c_ << 3)) = v_;                                    \
    }                                                                               \
  } while (0)

// MFMA layer over x_tile, K=256 (weight rows offset by 128 k-entries, stride 384)
#define LAYER256(WT, ACC)                                                           \
  do {                                                                              \
    const uint16_t* wr0_ = (WT) + (w * 32 + l15) * 384 + 128 + lg * 8;              \
    const uint16_t* wr1_ = (WT) + (w * 32 + 16 + l15) * 384 + 128 + lg * 8;         \
    _Pragma("unroll 2") for (int ks = 0; ks < 8; ++ks) {                            \
      bf16x8 bA_ = *(const bf16x8*)(wr0_ + ks * 32);                                \
      bf16x8 bB_ = *(const bf16x8*)(wr1_ + ks * 32);                                \
      _Pragma("unroll") for (int m = 0; m < 3; ++m) {                               \
        bf16x8 a_ = *(const bf16x8*)(xt + (m * 16 + l15) * XP2 + ks * 32 + lg * 8); \
        ACC[m][0] = mfma16(a_, bA_, ACC[m][0]);                                     \
        ACC[m][1] = mfma16(a_, bB_, ACC[m][1]);                                     \
      }                                                                             \
    }                                                                               \
  } while (0)

// MFMA layer, K=128, A = ASRC (pitch MP)
#define LAYER128(WT, ASRC, ACC)                                                     \
  do {                                                                              \
    const uint16_t* wr0_ = (WT) + (w * 32 + l15) * 128 + lg * 8;                    \
    const uint16_t* wr1_ = (WT) + (w * 32 + 16 + l15) * 128 + lg * 8;               \
    _Pragma("unroll") for (int ks = 0; ks < 4; ++ks) {                              \
      bf16x8 bA_ = *(const bf16x8*)(wr0_ + ks * 32);                                \
      bf16x8 bB_ = *(const bf16x8*)(wr1_ + ks * 32);                                \
      _Pragma("unroll") for (int m = 0; m < 3; ++m) {                               \
        bf16x8 a_ = *(const bf16x8*)((ASRC) + (m * 16 + l15) * MP + ks * 32 + lg * 8); \
        ACC[m][0] = mfma16(a_, bA_, ACC[m][0]);                                     \
        ACC[m][1] = mfma16(a_, bB_, ACC[m][1]);                                     \
      }                                                                              \
    }                                                                               \
  } while (0)

// bias + gelu + bf16 store to DST (pitch MP)
#define GSTORE(ACC, BIAS, DST)                                                      \
  do {                                                                              \
    float bA_ = (BIAS)[w * 32 + l15];                                               \
    float bB_ = (BIAS)[w * 32 + 16 + l15];                                          \
    _Pragma("unroll") for (int m = 0; m < 3; ++m)                                   \
    _Pragma("unroll") for (int r = 0; r < 4; ++r) {                                 \
      int row_ = m * 16 + lg * 4 + r;                                               \
      (DST)[row_ * MP + w * 32 + l15] = f2b(gelu_f(ACC[m][0][r] + bA_));            \
      (DST)[row_ * MP + w * 32 + 16 + l15] = f2b(gelu_f(ACC[m][1][r] + bB_));       \
    }                                                                               \
  } while (0)

#define ACC_INIT(ACC, CV)                                                           \
  do {                                                                              \
    float c0_ = (CV)[bn * 128 + w * 32 + l15];                                      \
    float c1_ = (CV)[bn * 128 + w * 32 + 16 + l15];                                 \
    _Pragma("unroll") for (int m = 0; m < 3; ++m) {                                 \
      ACC[m][0] = (f32x4){c0_, c0_, c0_, c0_};                                      \
      ACC[m][1] = (f32x4){c1_, c1_, c1_, c1_};                                      \
    }                                                                               \
  } while (0)

// ---------------- K1: node message MLP + masked sum + LN1 ----------------
// LDS map: xt [48][264] @0 (25344) | midA [48][136] @25344 (13056) |
//          midB overlays xt @0 | dh @38400 (512) | nbr @38912 (192) | amask @39104 (192)
__global__ __launch_bounds__(256, 4) void k_node(
    const float* __restrict__ hV, const float* __restrict__ hE,
    const int* __restrict__ eidx, const float* __restrict__ maskA,
    const float* __restrict__ bias1, const float* __restrict__ bias2,
    const float* __restrict__ bias3,
    const float* __restrict__ g1, const float* __restrict__ be1,
    const uint16_t* __restrict__ hVb, const float* __restrict__ C1,
    const uint16_t* __restrict__ W1t, const uint16_t* __restrict__ W2t,
    const uint16_t* __restrict__ W3t,
    float* __restrict__ hV1, uint16_t* __restrict__ hV1b) {
  __shared__ __align__(16) unsigned char lds[39296];
  uint16_t* xt = (uint16_t*)lds;
  uint16_t* midA = (uint16_t*)(lds + 25344);
  uint16_t* midB = (uint16_t*)lds;            // overlays xt (dead after layer 1)
  float* dh = (float*)(lds + 38400);
  int* nbr = (int*)(lds + 38912);
  float* amask = (float*)(lds + 39104);

  const int tid = threadIdx.x;
  const int lane = tid & 63;
  const int w = tid >> 6;
  const int l15 = lane & 15;
  const int lg = lane >> 4;
  const int bn = blockIdx.x;      // b*2048 + n
  const int b = bn >> 11;

  if (tid < 48) {
    nbr[tid] = (b << 11) + eidx[bn * 48 + tid];
    amask[tid] = maskA[bn * 48 + tid];
  }
  __syncthreads();

  BUILD_XT(hVb);
  __syncthreads();

  f32x4 acc1[3][2];
  ACC_INIT(acc1, C1);
  LAYER256(W1t, acc1);
  GSTORE(acc1, bias1, midA);
  __syncthreads();               // xt reads done; midB (=xt space) safe to write

  f32x4 acc2[3][2] = {};
  LAYER128(W2t, midA, acc2);
  GSTORE(acc2, bias2, midB);
  __syncthreads();

  f32x4 acc3[3][2] = {};
  LAYER128(W3t, midB, acc3);

  // masked column sums over the 48 edge rows
  {
    float bA = bias3[w * 32 + l15];
    float bB = bias3[w * 32 + 16 + l15];
    float s0 = 0.f, s1 = 0.f;
#pragma unroll
    for (int m = 0; m < 3; ++m)
#pragma unroll
      for (int r = 0; r < 4; ++r) {
        int row = m * 16 + lg * 4 + r;
        float mk = amask[row];
        s0 += (acc3[m][0][r] + bA) * mk;
        s1 += (acc3[m][1][r] + bB) * mk;
      }
    s0 += __shfl_xor(s0, 16); s0 += __shfl_xor(s0, 32);
    s1 += __shfl_xor(s1, 16); s1 += __shfl_xor(s1, 32);
    if (lg == 0) { dh[w * 32 + l15] = s0; dh[w * 32 + 16 + l15] = s1; }
  }
  __syncthreads();

  if (w == 0) {
    const float inv = 1.0f / 30.0f;
    float x0 = hV[bn * 128 + lane] + dh[lane] * inv;
    float x1 = hV[bn * 128 + 64 + lane] + dh[64 + lane] * inv;
    float s = x0 + x1, q = x0 * x0 + x1 * x1;
#pragma unroll
    for (int off = 1; off < 64; off <<= 1) {
      s += __shfl_xor(s, off);
      q += __shfl_xor(q, off);
    }
    float mean = s * (1.0f / 128.0f);
    float var = q * (1.0f / 128.0f) - mean * mean;
    float rstd = rsqrtf(var + 1e-5f);
    float y0 = (x0 - mean) * rstd * g1[lane] + be1[lane];
    float y1 = (x1 - mean) * rstd * g1[64 + lane] + be1[64 + lane];
    hV1[bn * 128 + lane] = y0;
    hV1[bn * 128 + 64 + lane] = y1;
    hV1b[bn * 128 + lane] = f2b(y0);
    hV1b[bn * 128 + 64 + lane] = f2b(y1);
  }
}

// ---------------- K2: position-wise FFN + LN2 + mask_V ----------------
__global__ __launch_bounds__(256, 2) void k_ffn(
    const float* __restrict__ hV1, const uint16_t* __restrict__ hV1b,
    const float* __restrict__ maskV,
    const float* __restrict__ bdin, const float* __restrict__ bdout,
    const float* __restrict__ g2, const float* __restrict__ be2,
    const uint16_t* __restrict__ WdInT, const uint16_t* __restrict__ WdOutT,
    float* __restrict__ outV, uint16_t* __restrict__ hV2b) {
  __shared__ __align__(16) unsigned char lds[20992];
  uint16_t* xa = (uint16_t*)lds;             // [16][136]
  uint16_t* mf = (uint16_t*)(lds + 4352);    // [16][520]
  float* epi = (float*)(lds + 4352);         // [16][132] overlays mf (post-barrier)

  const int tid = threadIdx.x;
  const int lane = tid & 63;
  const int w = tid >> 6;
  const int l15 = lane & 15;
  const int lg = lane >> 4;
  const int node0 = blockIdx.x * 16;

  {
    int row = tid >> 4, c = tid & 15;
    *(uint4*)(xa + row * 136 + (c << 3)) =
        *(const uint4*)(hV1b + (node0 + row) * 128 + (c << 3));
  }
  __syncthreads();

  // layer A: [16x128] @ [128x512]
  f32x4 acc[8] = {};
  {
    const uint16_t* ar = xa + l15 * 136 + lg * 8;
#pragma unroll
    for (int ks = 0; ks < 4; ++ks) {
      bf16x8 a = *(const bf16x8*)(ar + ks * 32);
#pragma unroll
      for (int j = 0; j < 8; ++j) {
        bf16x8 bb = *(const bf16x8*)(WdInT + ((w * 8 + j) * 16 + l15) * 128 + ks * 32 + lg * 8);
        acc[j] = mfma16(a, bb, acc[j]);
      }
    }
  }
#pragma unroll
  for (int j = 0; j < 8; ++j) {
    int col = (w * 8 + j) * 16 + l15;
    float bs = bdin[col];
#pragma unroll
    for (int r = 0; r < 4; ++r) {
      int row = lg * 4 + r;
      mf[row * FFP + col] = f2b(gelu_f(acc[j][r] + bs));
    }
  }
  __syncthreads();

  // layer B: [16x512] @ [512x128]
  f32x4 acc2[2] = {};
  {
    const uint16_t* mr = mf + l15 * FFP + lg * 8;
#pragma unroll 4
    for (int ks = 0; ks < 16; ++ks) {
      bf16x8 a = *(const bf16x8*)(mr + ks * 32);
#pragma unroll
      for (int t = 0; t < 2; ++t) {
        bf16x8 bb = *(const bf16x8*)(WdOutT + ((w * 2 + t) * 16 + l15) * 512 + ks * 32 + lg * 8);
        acc2[t] = mfma16(a, bb, acc2[t]);
      }
    }
  }
  __syncthreads();  // all mf reads done before epi overlays it
#pragma unroll
  for (int t = 0; t < 2; ++t) {
    int col = (w * 2 + t) * 16 + l15;
    float bs = bdout[col];
#pragma unroll
    for (int r = 0; r < 4; ++r) {
      int row = lg * 4 + r;
      epi[row * EPIP + col] = acc2[t][r] + bs;
    }
  }
  __syncthreads();

  // per-node LN2 + mask_V; wave w handles rows 4w..4w+3
#pragma unroll
  for (int rr = 0; rr < 4; ++rr) {
    int row = w * 4 + rr;
    int node = node0 + row;
    float x0 = epi[row * EPIP + lane] + hV1[node * 128 + lane];
    float x1 = epi[row * EPIP + 64 + lane] + hV1[node * 128 + 64 + lane];
    float s = x0 + x1, q = x0 * x0 + x1 * x1;
#pragma unroll
    for (int off = 1; off < 64; off <<= 1) {
      s += __shfl_xor(s, off);
      q += __shfl_xor(q, off);
    }
    float mean = s * (1.0f / 128.0f);
    float var = q * (1.0f / 128.0f) - mean * mean;
    float rstd = rsqrtf(var + 1e-5f);
    float mv = maskV[node];
    float y0 = mv * ((x0 - mean) * rstd * g2[lane] + be2[lane]);
    float y1 = mv * ((x1 - mean) * rstd * g2[64 + lane] + be2[64 + lane]);
    outV[node * 128 + lane] = y0;
    outV[node * 128 + 64 + lane] = y1;
    hV2b[node * 128 + lane] = f2b(y0);
    hV2b[node * 128 + 64 + lane] = f2b(y1);
  }
}

// ---------------- K3: edge MLP + residual + LN3 ----------------
// LDS map: xt @0 (25344) | midA @25344 (13056) | midB overlays xt @0 |
//          epi [48][132] f32 overlays xt @0 (25344) | nbr @38400 (192)
__global__ __launch_bounds__(256, 4) void k_edge(
    const float* __restrict__ hE, const int* __restrict__ eidx,
    const float* __restrict__ bias1, const float* __restrict__ bias2,
    const float* __restrict__ bias3,
    const float* __restrict__ g3, const float* __restrict__ be3,
    const uint16_t* __restrict__ hV2b, const float* __restrict__ C2,
    const uint16_t* __restrict__ W1t, const uint16_t* __restrict__ W2t,
    const uint16_t* __restrict__ W3t,
    float* __restrict__ outE) {
  __shared__ __align__(16) unsigned char lds[38592];
  uint16_t* xt = (uint16_t*)lds;
  uint16_t* midA = (uint16_t*)(lds + 25344);
  uint16_t* midB = (uint16_t*)lds;
  float* epi = (float*)lds;                  // [48][132] f32, after last midB read
  int* nbr = (int*)(lds + 38400);

  const int tid = threadIdx.x;
  const int lane = tid & 63;
  const int w = tid >> 6;
  const int l15 = lane & 15;
  const int lg = lane >> 4;
  const int bn = blockIdx.x;
  const int b = bn >> 11;

  if (tid < 48) nbr[tid] = (b << 11) + eidx[bn * 48 + tid];
  __syncthreads();

  BUILD_XT(hV2b);
  __syncthreads();

  f32x4 acc1[3][2];
  ACC_INIT(acc1, C2);
  LAYER256(W1t, acc1);
  GSTORE(acc1, bias1, midA);
  __syncthreads();

  f32x4 acc2[3][2] = {};
  LAYER128(W2t, midA, acc2);
  GSTORE(acc2, bias2, midB);
  __syncthreads();

  f32x4 acc3[3][2] = {};
  LAYER128(W3t, midB, acc3);
  __syncthreads();  // all midB reads done before epi overlays it

  {
    float bA = bias3[w * 32 + l15];
    float bB = bias3[w * 32 + 16 + l15];
#pragma unroll
    for (int m = 0; m < 3; ++m)
#pragma unroll
      for (int r = 0; r < 4; ++r) {
        int row = m * 16 + lg * 4 + r;
        epi[row * EPIP + w * 32 + l15] = acc3[m][0][r] + bA;
        epi[row * EPIP + w * 32 + 16 + l15] = acc3[m][1][r] + bB;
      }
  }
  __syncthreads();

  // per-edge-row LN3 with f32 residual; wave w handles rows 12w..12w+11
#pragma unroll
  for (int rr = 0; rr < 12; ++rr) {
    int row = w * 12 + rr;
    int e = bn * 48 + row;
    float x0 = epi[row * EPIP + lane] + hE[(size_t)e * 128 + lane];
    float x1 = epi[row * EPIP + 64 + lane] + hE[(size_t)e * 128 + 64 + lane];
    float s = x0 + x1, q = x0 * x0 + x1 * x1;
#pragma unroll
    for (int off = 1; off < 64; off <<= 1) {
      s += __shfl_xor(s, off);
      q += __shfl_xor(q, off);
    }
    float mean = s * (1.0f / 128.0f);
    float var = q * (1.0f / 128.0f) - mean * mean;
    float rstd = rsqrtf(var + 1e-5f);
    float y0 = (x0 - mean) * rstd * g3[lane] + be3[lane];
    float y1 = (x1 - mean) * rstd * g3[64 + lane] + be3[64 + lane];
    outE[(size_t)e * 128 + lane] = y0;
    outE[(size_t)e * 128 + 64 + lane] = y1;
  }
}

extern "C" void kernel_launch(void* const* d_in, const int* in_sizes, int n_in,
                              void* d_out, int out_size, void* d_ws, size_t ws_size,
                              hipStream_t stream) {
  const float* hV = (const float*)d_in[0];
  const float* hE = (const float*)d_in[1];
  const int* eidx = (const int*)d_in[2];
  const float* maskV = (const float*)d_in[3];
  const float* maskA = (const float*)d_in[4];
  const float* W1 = (const float*)d_in[5];   const float* b1 = (const float*)d_in[6];
  const float* W2 = (const float*)d_in[7];   const float* b2 = (const float*)d_in[8];
  const float* W3 = (const float*)d_in[9];   const float* b3 = (const float*)d_in[10];
  const float* WdIn = (const float*)d_in[11];  const float* bdin = (const float*)d_in[12];
  const float* WdOut = (const float*)d_in[13]; const float* bdout = (const float*)d_in[14];
  const float* W11 = (const float*)d_in[15]; const float* b11 = (const float*)d_in[16];
  const float* W12 = (const float*)d_in[17]; const float* b12 = (const float*)d_in[18];
  const float* W13 = (const float*)d_in[19]; const float* b13 = (const float*)d_in[20];
  const float* n1g = (const float*)d_in[21]; const float* n1b = (const float*)d_in[22];
  const float* n2g = (const float*)d_in[23]; const float* n2b = (const float*)d_in[24];
  const float* n3g = (const float*)d_in[25]; const float* n3b = (const float*)d_in[26];

  char* ws = (char*)d_ws;
  uint16_t* hVb    = (uint16_t*)(ws + 0);         // 1,048,576 B
  uint16_t* W1t    = (uint16_t*)(ws + 1048576);   // 98,304
  uint16_t* W2t    = (uint16_t*)(ws + 1146880);   // 32,768
  uint16_t* W3t    = (uint16_t*)(ws + 1179648);   // 32,768
  uint16_t* WdInT  = (uint16_t*)(ws + 1212416);   // 131,072
  uint16_t* WdOutT = (uint16_t*)(ws + 1343488);   // 131,072
  uint16_t* W11t   = (uint16_t*)(ws + 1474560);   // 98,304
  uint16_t* W12t   = (uint16_t*)(ws + 1572864);   // 32,768
  uint16_t* W13t   = (uint16_t*)(ws + 1605632);   // 32,768
  float*    hV1    = (float*)(ws + 1638400);      // 2,097,152 (f32)
  uint16_t* hV1b   = (uint16_t*)(ws + 3735552);   // 1,048,576
  uint16_t* hV2b   = (uint16_t*)(ws + 4784128);   // 1,048,576
  float*    C1     = (float*)(ws + 5832704);      // 2,097,152 (f32)
  float*    C2     = (float*)(ws + 7929856);      // 2,097,152 (f32)  total ~10.0 MB

  float* outV = (float*)d_out;
  float* outE = (float*)d_out + 524288;

  k_prep<<<3200, 256, 0, stream>>>(hV, W1, W2, W3, WdIn, WdOut, W11, W12, W13,
                                   hVb, W1t, W2t, W3t, WdInT, WdOutT, W11t, W12t, W13t);
  k_vec<<<64, 256, 0, stream>>>(hVb, W1t, C1);
  k_node<<<4096, 256, 0, stream>>>(hV, hE, eidx, maskA, b1, b2, b3, n1g, n1b,
                                   hVb, C1, W1t, W2t, W3t, hV1, hV1b);
  k_ffn<<<256, 256, 0, stream>>>(hV1, hV1b, maskV, bdin, bdout, n2g, n2b,
                                 WdInT, WdOutT, outV, hV2b);
  k_vec<<<64, 256, 0, stream>>>(hV2b, W11t, C2);
  k_edge<<<4096, 256, 0, stream>>>(hE, eidx, b11, b12, b13, n3g, n3b,
                                   hV2b, C2, W11t, W12t, W13t, outE);
}